// Round 1
// baseline (22523.878 us; speedup 1.0000x reference)
//
#include <hip/hip_runtime.h>
#include <hip/hip_bf16.h>

#define NFLOW 20000
#define NMEMB 5000
#define EFFN  100000
#define EMFN  80000

using bf16 = __hip_bfloat16;

__device__ __forceinline__ float fcomp(const float4 v, int i) {
  return i == 0 ? v.x : (i == 1 ? v.y : (i == 2 ? v.z : v.w));
}

__device__ __forceinline__ void atomicMaxFloat(float* addr, float val) {
  int* ai = (int*)addr;
  int old = __float_as_int(*addr);
  while (__int_as_float(old) < val) {
    int assumed = old;
    old = atomicCAS(ai, assumed, __float_as_int(val));
    if (old == assumed) break;
  }
}

// ---------------- init: zero xc/aggr, m=-inf, z=0 ----------------
__global__ __launch_bounds__(256) void k_init(float* __restrict__ xc,
                                              float* __restrict__ aggr,
                                              float* __restrict__ m,
                                              float* __restrict__ z) {
  int i = blockIdx.x * 256 + threadIdx.x;
  if (i < NFLOW * 64) { xc[i] = 0.f; aggr[i] = 0.f; }
  if (i < NFLOW) { m[i] = __int_as_float(0xff800000); z[i] = 0.f; }
}

// ---------------- Y(N,64) = X(N,64) @ W(64,64) ----------------
__global__ __launch_bounds__(256) void k_linear64(const float* __restrict__ X,
                                                  const float* __restrict__ W,
                                                  float* __restrict__ Y, int N) {
  __shared__ float Ws[64 * 64];
  __shared__ float Xs[4][65];
  const int t = threadIdx.x;
  for (int i = t; i < 4096; i += 256) Ws[i] = W[i];
  const int r = t >> 6, f = t & 63;
  const int n = blockIdx.x * 4 + r;
  Xs[r][f] = (n < N) ? X[n * 64 + f] : 0.f;
  __syncthreads();
  if (n < N) {
    float s = 0.f;
#pragma unroll
    for (int d = 0; d < 64; ++d) s += Xs[r][d] * Ws[d * 64 + f];
    Y[n * 64 + f] = s;
  }
}

// ---------------- attention scores + segment max ----------------
__global__ __launch_bounds__(256) void k_score(const float* __restrict__ q,
                                               const float* __restrict__ kb,
                                               const float* __restrict__ ea_mf,
                                               const int* __restrict__ ei_mf,
                                               const float* __restrict__ We,
                                               float* __restrict__ score,
                                               float* __restrict__ m) {
  const int t = threadIdx.x;
  const int e = blockIdx.x * 4 + (t >> 6);
  const int lane = t & 63;
  if (e >= EMFN) return;
  const int sm = ei_mf[e];
  const int df = ei_mf[EMFN + e];
  float ke = kb[sm * 64 + lane];
#pragma unroll
  for (int i = 0; i < 6; ++i) ke += ea_mf[e * 6 + i] * We[i * 64 + lane];
  float s = q[df * 64 + lane] * ke;
#pragma unroll
  for (int o = 32; o; o >>= 1) s += __shfl_xor(s, o, 64);
  s *= 0.125f;  // 1/sqrt(64)
  if (lane == 0) {
    score[e] = s;
    atomicMaxFloat(&m[df], s);
  }
}

// ---------------- a=exp(score-m); z += a; xc += a*v[src] ----------------
__global__ __launch_bounds__(256) void k_az(const float* __restrict__ score,
                                            const float* __restrict__ m,
                                            const int* __restrict__ ei_mf,
                                            const float* __restrict__ vb,
                                            float* __restrict__ z,
                                            float* __restrict__ xc) {
  const int t = threadIdx.x;
  const int e = blockIdx.x * 4 + (t >> 6);
  const int lane = t & 63;
  if (e >= EMFN) return;
  const int sm = ei_mf[e];
  const int df = ei_mf[EMFN + e];
  const float a = expf(score[e] - m[df]);
  if (lane == 0) atomicAdd(&z[df], a);
  atomicAdd(&xc[df * 64 + lane], a * vb[sm * 64 + lane]);
}

// ---------------- fused edge MLP + einsum contraction + segment sum --------
// msg[e,f] = sum_k h1[e,k]*(sum_d x[e,d]*Wk2[k,d*64+f]) + sum_d x[e,d]*bk2[d*64+f]
__device__ __forceinline__ void accumP(const float* __restrict__ xs,
                                       const float* __restrict__ wr,
                                       int eT, int f0, float P[4][4]) {
#pragma unroll
  for (int d = 0; d < 64; d += 4) {
    float4 xa[4];
#pragma unroll
    for (int i = 0; i < 4; ++i)
      xa[i] = *(const float4*)(xs + (eT + i) * 68 + d);
#pragma unroll
    for (int dd = 0; dd < 4; ++dd) {
      float4 wv = *(const float4*)(wr + (d + dd) * 64 + f0);
#pragma unroll
      for (int i = 0; i < 4; ++i) {
        float x = fcomp(xa[i], dd);
        P[i][0] += x * wv.x;
        P[i][1] += x * wv.y;
        P[i][2] += x * wv.z;
        P[i][3] += x * wv.w;
      }
    }
  }
}

__global__ __launch_bounds__(256) void k_edge(
    const float* __restrict__ x_flow, const float* __restrict__ ea_ff,
    const int* __restrict__ ei_ff,
    const float* __restrict__ Wk0, const float* __restrict__ bk0,
    const float* __restrict__ Wk1, const float* __restrict__ bk1,
    const float* __restrict__ Wk2, const float* __restrict__ bk2,
    float* __restrict__ aggr) {
  __shared__ bf16 h0s[64][512];   // 64 KB; phase2: xs[64][68] + wbuf[2][4096]
  __shared__ bf16 h1s[64][512];   // 64 KB; phase1 start: Wk0 staging (12 KB)
  __shared__ float eas[64][6];
  const int t = threadIdx.x;
  const int e0g = blockIdx.x * 64;

  // ---- stage Wk0 (into h1s region as float) and ea tile
  float* w0s = (float*)h1s;
  for (int i = t; i < 6 * 512; i += 256) w0s[i] = Wk0[i];
  for (int i = t; i < 64 * 6; i += 256) {
    int g = e0g * 6 + i;
    ((float*)eas)[i] = (g < EFFN * 6) ? ea_ff[g] : 0.f;
  }
  __syncthreads();

  // ---- h0 = relu(ea @ Wk0 + bk0) -> bf16 LDS
  for (int idx = t; idx < 64 * 512; idx += 256) {
    int e = idx >> 9, kk = idx & 511;
    float s = bk0[kk];
#pragma unroll
    for (int i = 0; i < 6; ++i) s += eas[e][i] * w0s[i * 512 + kk];
    h0s[e][kk] = __float2bfloat16(fmaxf(s, 0.f));
  }
  __syncthreads();

  // ---- h1 = relu(h0 @ Wk1 + bk1) -> bf16 LDS (Wk1 streamed from L2)
  {
    const int kq = t & 127, eh = t >> 7;
    const int k0 = kq * 4;
    for (int p = 0; p < 8; ++p) {
      const int eb = p * 8 + eh * 4;
      float acc[4][4];
#pragma unroll
      for (int i = 0; i < 4; ++i)
#pragma unroll
        for (int jj = 0; jj < 4; ++jj) acc[i][jj] = bk1[k0 + jj];
#pragma unroll 4
      for (int j = 0; j < 512; ++j) {
        float4 w = *(const float4*)(Wk1 + j * 512 + k0);
#pragma unroll
        for (int i = 0; i < 4; ++i) {
          float h = __bfloat162float(h0s[eb + i][j]);
          acc[i][0] += h * w.x;
          acc[i][1] += h * w.y;
          acc[i][2] += h * w.z;
          acc[i][3] += h * w.w;
        }
      }
#pragma unroll
      for (int i = 0; i < 4; ++i)
#pragma unroll
        for (int jj = 0; jj < 4; ++jj)
          h1s[eb + i][k0 + jj] = __float2bfloat16(fmaxf(acc[i][jj], 0.f));
    }
  }
  __syncthreads();

  // ---- phase 2: contraction. Reuse h0s region: xs[64][68] + wbuf[2][4096]
  float* xs = (float*)h0s;
  float* wbuf = ((float*)h0s) + 64 * 68;

  for (int idx = t; idx < 64 * 64; idx += 256) {
    int e = idx >> 6, d = idx & 63;
    int eg = e0g + e;
    int src = (eg < EFFN) ? ei_ff[eg] : 0;
    xs[e * 68 + d] = (eg < EFFN) ? x_flow[src * 64 + d] : 0.f;
  }
  {
    const float4* b4 = (const float4*)bk2;
    const float4* w4 = (const float4*)Wk2;
    float4* d0 = (float4*)wbuf;
    float4* d1 = (float4*)(wbuf + 4096);
    for (int i = t; i < 1024; i += 256) { d0[i] = b4[i]; d1[i] = w4[i]; }
  }
  __syncthreads();

  const int eT = (t >> 4) * 4;
  const int f0 = (t & 15) * 4;
  float msg[4][4];
  {  // bias pass from wbuf[0] (bk2), coefficient 1
    float P[4][4] = {};
    accumP(xs, wbuf, eT, f0, P);
#pragma unroll
    for (int i = 0; i < 4; ++i)
#pragma unroll
      for (int jj = 0; jj < 4; ++jj) msg[i][jj] = P[i][jj];
  }
  __syncthreads();  // wbuf[0] free for k=0's prefetch write

  float4 rr[4];
  for (int k = 0; k < 512; ++k) {
    const int cur = (k + 1) & 1;  // row k lives in wbuf[cur]
    if (k + 1 < 512) {            // issue next-row loads early (T14)
      const float4* srcp = (const float4*)(Wk2 + (size_t)(k + 1) * 4096);
#pragma unroll
      for (int i = 0; i < 4; ++i) rr[i] = srcp[t + i * 256];
    }
    float P[4][4] = {};
    accumP(xs, wbuf + cur * 4096, eT, f0, P);
#pragma unroll
    for (int i = 0; i < 4; ++i) {
      float h = __bfloat162float(h1s[eT + i][k]);
#pragma unroll
      for (int jj = 0; jj < 4; ++jj) msg[i][jj] += h * P[i][jj];
    }
    if (k + 1 < 512) {  // write-late into the other buffer
      float4* dstp = (float4*)(wbuf + (cur ^ 1) * 4096);
#pragma unroll
      for (int i = 0; i < 4; ++i) dstp[t + i * 256] = rr[i];
    }
    __syncthreads();
  }

#pragma unroll
  for (int i = 0; i < 4; ++i) {
    int eg = e0g + eT + i;
    if (eg < EFFN) {
      int dst = ei_ff[EFFN + eg];
#pragma unroll
      for (int jj = 0; jj < 4; ++jj)
        atomicAdd(&aggr[dst * 64 + f0 + jj], msg[i][jj]);
    }
  }
}

// ---------------- final: Wroot/Wo applies, FiLM, silu ----------------
__global__ __launch_bounds__(256) void k_final(
    const float* __restrict__ x_flow, const float* __restrict__ aggr,
    const float* __restrict__ xc, const float* __restrict__ z,
    const float* __restrict__ Wroot, const float* __restrict__ broot,
    const float* __restrict__ Wo, const float* __restrict__ bo,
    const float* __restrict__ tau, const float* __restrict__ Wt1,
    const float* __restrict__ bt1, const float* __restrict__ Wt2,
    const float* __restrict__ bt2, float* __restrict__ out) {
  __shared__ float WoS[4096], WrS[4096], ssS[128], tembS[64];
  __shared__ float xcnS[4][65], xfS[4][65];
  const int t = threadIdx.x;
  for (int i = t; i < 4096; i += 256) { WoS[i] = Wo[i]; WrS[i] = Wroot[i]; }
  if (t < 64) {
    float y = tau[0] * Wt1[t] + bt1[t];
    tembS[t] = y / (1.f + expf(-y));
  }
  __syncthreads();
  if (t < 128) {
    float s = bt2[t];
#pragma unroll
    for (int d = 0; d < 64; ++d) s += tembS[d] * Wt2[d * 128 + t];
    ssS[t] = s;
  }
  const int r = t >> 6, f = t & 63;
  const int n = blockIdx.x * 4 + r;
  if (n < NFLOW) {
    float zr = z[n];
    xcnS[r][f] = xc[n * 64 + f] / (zr + 1e-9f);
    xfS[r][f] = x_flow[n * 64 + f];
  }
  __syncthreads();
  if (n < NFLOW) {
    float cross = bo[f], root = broot[f];
#pragma unroll
    for (int d = 0; d < 64; ++d) {
      cross += xcnS[r][d] * WoS[d * 64 + f];
      root += xfS[r][d] * WrS[d * 64 + f];
    }
    float g = root + aggr[n * 64 + f] + cross;
    g = fmaxf(g, 0.f);
    float y = g * (1.f + ssS[f]) + ssS[64 + f];
    out[n * 64 + f] = y / (1.f + expf(-y));
  }
}

extern "C" void kernel_launch(void* const* d_in, const int* in_sizes, int n_in,
                              void* d_out, int out_size, void* d_ws, size_t ws_size,
                              hipStream_t stream) {
  const float* x_flow = (const float*)d_in[0];
  const float* x_memb = (const float*)d_in[1];
  const float* ea_ff  = (const float*)d_in[2];
  const float* ea_mf  = (const float*)d_in[3];
  const float* tau    = (const float*)d_in[4];
  const int*   ei_ff  = (const int*)d_in[5];
  const int*   ei_mf  = (const int*)d_in[6];
  const float* Wk0 = (const float*)d_in[7],  *bk0 = (const float*)d_in[8];
  const float* Wk1 = (const float*)d_in[9],  *bk1 = (const float*)d_in[10];
  const float* Wk2 = (const float*)d_in[11], *bk2 = (const float*)d_in[12];
  const float* Wroot = (const float*)d_in[13], *broot = (const float*)d_in[14];
  const float* Wq = (const float*)d_in[15];
  const float* Wkk = (const float*)d_in[16];
  const float* Wv = (const float*)d_in[17];
  const float* We = (const float*)d_in[18];
  const float* Wo = (const float*)d_in[19], *bo = (const float*)d_in[20];
  const float* Wt1 = (const float*)d_in[21], *bt1 = (const float*)d_in[22];
  const float* Wt2 = (const float*)d_in[23], *bt2 = (const float*)d_in[24];

  float* ws = (float*)d_ws;
  float* xc    = ws;                    // NF*64
  float* aggr  = xc + NFLOW * 64;       // NF*64
  float* m     = aggr + NFLOW * 64;     // NF
  float* z     = m + NFLOW;             // NF
  float* score = z + NFLOW;             // EMF
  float* q     = score + EMFN;          // NF*64
  float* kb    = q + NFLOW * 64;        // NM*64
  float* vb    = kb + NMEMB * 64;       // NM*64
  float* out   = (float*)d_out;

  k_init<<<(NFLOW * 64 + 255) / 256, 256, 0, stream>>>(xc, aggr, m, z);
  k_linear64<<<(NFLOW + 3) / 4, 256, 0, stream>>>(x_flow, Wq, q, NFLOW);
  k_linear64<<<(NMEMB + 3) / 4, 256, 0, stream>>>(x_memb, Wkk, kb, NMEMB);
  k_linear64<<<(NMEMB + 3) / 4, 256, 0, stream>>>(x_memb, Wv, vb, NMEMB);
  k_score<<<EMFN / 4, 256, 0, stream>>>(q, kb, ea_mf, ei_mf, We, score, m);
  k_az<<<EMFN / 4, 256, 0, stream>>>(score, m, ei_mf, vb, z, xc);
  k_edge<<<(EFFN + 63) / 64, 256, 0, stream>>>(x_flow, ea_ff, ei_ff,
                                               Wk0, bk0, Wk1, bk1, Wk2, bk2, aggr);
  k_final<<<(NFLOW + 3) / 4, 256, 0, stream>>>(x_flow, aggr, xc, z, Wroot, broot,
                                               Wo, bo, tau, Wt1, bt1, Wt2, bt2, out);
}

// Round 2
// 1813.220 us; speedup vs baseline: 12.4220x; 12.4220x over previous
//
#include <hip/hip_runtime.h>
#include <hip/hip_bf16.h>

#define NFLOW 20000
#define NMEMB 5000
#define EFFN  100000
#define EMFN  80000

using short8 = __attribute__((ext_vector_type(8))) short;
using f32x16 = __attribute__((ext_vector_type(16))) float;

__device__ __forceinline__ short bf16s(float f) {
  __hip_bfloat16 h = __float2bfloat16(f);
  return *reinterpret_cast<short*>(&h);
}

__device__ __forceinline__ void gl_lds16(const void* g, void* l) {
  __builtin_amdgcn_global_load_lds(
      (const __attribute__((address_space(1))) unsigned int*)g,
      (__attribute__((address_space(3))) unsigned int*)l, 16, 0, 0);
}

__device__ __forceinline__ void atomicMaxFloat(float* addr, float val) {
  int* ai = (int*)addr;
  int old = __float_as_int(*addr);
  while (__int_as_float(old) < val) {
    int assumed = old;
    old = atomicCAS(ai, assumed, __float_as_int(val));
    if (old == assumed) break;
  }
}

// ---------------- init ----------------
__global__ __launch_bounds__(256) void k_init(float* __restrict__ xc,
                                              float* __restrict__ aggr,
                                              float* __restrict__ m,
                                              float* __restrict__ z,
                                              float* __restrict__ xsum) {
  int i = blockIdx.x * 256 + threadIdx.x;
  if (i < NFLOW * 64) { xc[i] = 0.f; aggr[i] = 0.f; xsum[i] = 0.f; }
  if (i < NFLOW) { m[i] = __int_as_float(0xff800000); z[i] = 0.f; }
}

// ------------- transpose+cvt: out[c*R+r] = bf16(in[r*C+c]) -------------
__global__ __launch_bounds__(256) void k_transpose(const float* __restrict__ in,
                                                   unsigned short* __restrict__ out,
                                                   int R, int C) {
  __shared__ unsigned short tile[64][66];
  const int t = threadIdx.x;
  const int r0 = blockIdx.x * 64, c0 = blockIdx.y * 64;
  {
    int r = t >> 2;
    int cb = (t & 3) * 16;
#pragma unroll
    for (int q = 0; q < 4; ++q) {
      float4 v = *(const float4*)(in + (size_t)(r0 + r) * C + c0 + cb + q * 4);
      tile[r][cb + q * 4 + 0] = (unsigned short)bf16s(v.x);
      tile[r][cb + q * 4 + 1] = (unsigned short)bf16s(v.y);
      tile[r][cb + q * 4 + 2] = (unsigned short)bf16s(v.z);
      tile[r][cb + q * 4 + 3] = (unsigned short)bf16s(v.w);
    }
  }
  __syncthreads();
  {
    int c = t >> 2;
    int rb = (t & 3) * 16;
#pragma unroll
    for (int q = 0; q < 4; ++q) {
      int r = rb + q * 4;
      ushort4 v = make_ushort4(tile[r][c], tile[r + 1][c], tile[r + 2][c], tile[r + 3][c]);
      *(ushort4*)(out + (size_t)(c0 + c) * R + r0 + r) = v;
    }
  }
}

// ---------------- Y(N,64) = X(N,64) @ W(64,64) ----------------
__global__ __launch_bounds__(256) void k_linear64(const float* __restrict__ X,
                                                  const float* __restrict__ W,
                                                  float* __restrict__ Y, int N) {
  __shared__ float Ws[64 * 64];
  __shared__ float Xs[4][65];
  const int t = threadIdx.x;
  for (int i = t; i < 4096; i += 256) Ws[i] = W[i];
  const int r = t >> 6, f = t & 63;
  const int n = blockIdx.x * 4 + r;
  Xs[r][f] = (n < N) ? X[n * 64 + f] : 0.f;
  __syncthreads();
  if (n < N) {
    float s = 0.f;
#pragma unroll
    for (int d = 0; d < 64; ++d) s += Xs[r][d] * Ws[d * 64 + f];
    Y[n * 64 + f] = s;
  }
}

// ---------------- attention scores + segment max ----------------
__global__ __launch_bounds__(256) void k_score(const float* __restrict__ q,
                                               const float* __restrict__ kb,
                                               const float* __restrict__ ea_mf,
                                               const int* __restrict__ ei_mf,
                                               const float* __restrict__ We,
                                               float* __restrict__ score,
                                               float* __restrict__ m) {
  const int t = threadIdx.x;
  const int e = blockIdx.x * 4 + (t >> 6);
  const int lane = t & 63;
  if (e >= EMFN) return;
  const int sm = ei_mf[e];
  const int df = ei_mf[EMFN + e];
  float ke = kb[sm * 64 + lane];
#pragma unroll
  for (int i = 0; i < 6; ++i) ke += ea_mf[e * 6 + i] * We[i * 64 + lane];
  float s = q[df * 64 + lane] * ke;
#pragma unroll
  for (int o = 32; o; o >>= 1) s += __shfl_xor(s, o, 64);
  s *= 0.125f;
  if (lane == 0) {
    score[e] = s;
    atomicMaxFloat(&m[df], s);
  }
}

// ---------------- a=exp(score-m); z += a; xc += a*v[src] ----------------
__global__ __launch_bounds__(256) void k_az(const float* __restrict__ score,
                                            const float* __restrict__ m,
                                            const int* __restrict__ ei_mf,
                                            const float* __restrict__ vb,
                                            float* __restrict__ z,
                                            float* __restrict__ xc) {
  const int t = threadIdx.x;
  const int e = blockIdx.x * 4 + (t >> 6);
  const int lane = t & 63;
  if (e >= EMFN) return;
  const int sm = ei_mf[e];
  const int df = ei_mf[EMFN + e];
  const float a = expf(score[e] - m[df]);
  if (lane == 0) atomicAdd(&z[df], a);
  atomicAdd(&xc[df * 64 + lane], a * vb[sm * 64 + lane]);
}

// ============ fused edge MLP + contraction (MFMA) ============
// LDS arena: R1 (69,632 B): {w0s|bk0s|eas} -> h1sT[512][68]bf16 (Bt_c @+34816) -> part[4][64][66]f32
//            R2 (65,536 B): h0s[64][64slots] swz bf16 -> {xs[64][68]f32 | Bt dbuf 2x16KB}
__global__ __launch_bounds__(256, 1) void k_edge(
    const float* __restrict__ x_flow, const float* __restrict__ ea_ff,
    const int* __restrict__ ei_ff,
    const float* __restrict__ Wk0, const float* __restrict__ bk0,
    const float* __restrict__ bk1,
    const unsigned short* __restrict__ Wk1T,   // [512 n][512 k] bf16
    const unsigned short* __restrict__ Wk2T,   // [64 f][32768 kappa] bf16
    float* __restrict__ aggr, float* __restrict__ xsum) {
  __shared__ __align__(16) char LDS[135168];
  char* R1 = LDS;
  char* R2 = LDS + 69632;
  const int t = threadIdx.x;
  const int w = t >> 6, lane = t & 63, half = lane >> 5;
  const int e0g = blockIdx.x * 64;

  // ---- stage Wk0, bk0, ea tile ----
  float* w0s  = (float*)R1;            // [6][512]
  float* bk0s = (float*)(R1 + 12288);  // [512]
  float* eas  = (float*)(R1 + 14336);  // [64][6]
  for (int i = t; i < 3072; i += 256) w0s[i] = Wk0[i];
  for (int i = t; i < 512; i += 256) bk0s[i] = bk0[i];
  for (int i = t; i < 384; i += 256) {
    int g = e0g * 6 + i;
    eas[i] = (g < EFFN * 6) ? ea_ff[g] : 0.f;
  }
  __syncthreads();

  // ---- h0 = relu(ea@Wk0+bk0) -> R2 swizzled bf16 ----
  {
    int e = t >> 2, c0 = (t & 3) * 128;
    float ea[6];
#pragma unroll
    for (int i = 0; i < 6; ++i) ea[i] = eas[e * 6 + i];
    for (int s8 = 0; s8 < 16; ++s8) {
      int kbase = c0 + s8 * 8;
      float s[8];
      float4 b0 = *(const float4*)(bk0s + kbase);
      float4 b1 = *(const float4*)(bk0s + kbase + 4);
      s[0]=b0.x; s[1]=b0.y; s[2]=b0.z; s[3]=b0.w; s[4]=b1.x; s[5]=b1.y; s[6]=b1.z; s[7]=b1.w;
#pragma unroll
      for (int i = 0; i < 6; ++i) {
        float4 w0 = *(const float4*)(w0s + i * 512 + kbase);
        float4 w1 = *(const float4*)(w0s + i * 512 + kbase + 4);
        s[0] = fmaf(ea[i], w0.x, s[0]); s[1] = fmaf(ea[i], w0.y, s[1]);
        s[2] = fmaf(ea[i], w0.z, s[2]); s[3] = fmaf(ea[i], w0.w, s[3]);
        s[4] = fmaf(ea[i], w1.x, s[4]); s[5] = fmaf(ea[i], w1.y, s[5]);
        s[6] = fmaf(ea[i], w1.z, s[6]); s[7] = fmaf(ea[i], w1.w, s[7]);
      }
      short8 v;
#pragma unroll
      for (int j = 0; j < 8; ++j) v[j] = bf16s(fmaxf(s[j], 0.f));
      int slot = (kbase >> 3) ^ (e & 15);
      *(short8*)(R2 + e * 1024 + slot * 16) = v;
    }
  }
  __syncthreads();

  // ---- h1 = relu(h0 @ Wk1 + bk1) -> h1sT[n][e] bf16 (2 passes of 256 n) ----
  char* BtC = R1 + 34816;  // [256 n][128 B]
  for (int pass = 0; pass < 2; ++pass) {
    const int np = pass * 256;
    f32x16 acc[2][2];
#pragma unroll
    for (int m = 0; m < 2; ++m)
#pragma unroll
      for (int n = 0; n < 2; ++n)
#pragma unroll
        for (int r = 0; r < 16; ++r) acc[m][n][r] = 0.f;
    for (int kc = 0; kc < 8; ++kc) {
#pragma unroll
      for (int i = 0; i < 8; ++i) {
        int row = w * 64 + i * 8 + (lane >> 3);
        int slot = (lane & 7) ^ (row & 7);
        const char* g = (const char*)Wk1T + (size_t)(np + row) * 1024 + kc * 128 + slot * 16;
        gl_lds16(g, BtC + (w * 64 + i * 8) * 128);
      }
      __syncthreads();
#pragma unroll
      for (int ks = 0; ks < 4; ++ks) {
        short8 a[2], b[2];
#pragma unroll
        for (int m = 0; m < 2; ++m) {
          int e = (lane & 31) + 32 * m;
          int slot = ((kc * 64 + ks * 16 + half * 8) >> 3) ^ (e & 15);
          a[m] = *(const short8*)(R2 + e * 1024 + slot * 16);
        }
#pragma unroll
        for (int n = 0; n < 2; ++n) {
          int nl = w * 64 + n * 32 + (lane & 31);
          int slot = (2 * ks + half) ^ (nl & 7);
          b[n] = *(const short8*)(BtC + nl * 128 + slot * 16);
        }
#pragma unroll
        for (int m = 0; m < 2; ++m)
#pragma unroll
          for (int n = 0; n < 2; ++n)
            acc[m][n] = __builtin_amdgcn_mfma_f32_32x32x16_bf16(a[m], b[n], acc[m][n], 0, 0, 0);
      }
      __syncthreads();
    }
    // epilogue: write h1sT rows np..np+255 (transposed, b64-packed)
#pragma unroll
    for (int n = 0; n < 2; ++n) {
      int nl = np + w * 64 + n * 32 + (lane & 31);
      float b1 = bk1[nl];
#pragma unroll
      for (int m = 0; m < 2; ++m) {
#pragma unroll
        for (int rq = 0; rq < 4; ++rq) {
          int e0 = 32 * m + 8 * rq + 4 * half;
          unsigned short u0 = (unsigned short)bf16s(fmaxf(acc[m][n][rq * 4 + 0] + b1, 0.f));
          unsigned short u1 = (unsigned short)bf16s(fmaxf(acc[m][n][rq * 4 + 1] + b1, 0.f));
          unsigned short u2 = (unsigned short)bf16s(fmaxf(acc[m][n][rq * 4 + 2] + b1, 0.f));
          unsigned short u3 = (unsigned short)bf16s(fmaxf(acc[m][n][rq * 4 + 3] + b1, 0.f));
          uint2 val = make_uint2((unsigned)u0 | ((unsigned)u1 << 16),
                                 (unsigned)u2 | ((unsigned)u3 << 16));
          *(uint2*)(R1 + nl * 136 + e0 * 2) = val;
        }
      }
    }
    __syncthreads();
  }

  // ---- stage xs (f32) + xsum atomics ----
  float* xs = (float*)R2;  // [64][68]
  {
    int row = t >> 2, c0 = (t & 3) * 16;
    int eg = e0g + row;
    bool valid = eg < EFFN;
    int src = valid ? ei_ff[eg] : 0;
    float4 v[4];
#pragma unroll
    for (int q = 0; q < 4; ++q) {
      v[q] = valid ? *(const float4*)(x_flow + (size_t)src * 64 + c0 + q * 4)
                   : make_float4(0.f, 0.f, 0.f, 0.f);
      *(float4*)(xs + row * 68 + c0 + q * 4) = v[q];
    }
    if (valid) {
      int dst = ei_ff[EFFN + eg];
#pragma unroll
      for (int q = 0; q < 4; ++q) {
        atomicAdd(&xsum[dst * 64 + c0 + q * 4 + 0], v[q].x);
        atomicAdd(&xsum[dst * 64 + c0 + q * 4 + 1], v[q].y);
        atomicAdd(&xsum[dst * 64 + c0 + q * 4 + 2], v[q].z);
        atomicAdd(&xsum[dst * 64 + c0 + q * 4 + 3], v[q].w);
      }
    }
  }
  __syncthreads();

  // ---- x into registers: xr[m][i][j] covers d0 = (32w+16i+8half)&63 ----
  float xr[2][2][8];
#pragma unroll
  for (int m = 0; m < 2; ++m)
#pragma unroll
    for (int i = 0; i < 2; ++i) {
      int row = (lane & 31) + 32 * m;
      int d0 = (32 * w + 16 * i + 8 * half) & 63;
      float4 p0 = *(const float4*)(xs + row * 68 + d0);
      float4 p1 = *(const float4*)(xs + row * 68 + d0 + 4);
      xr[m][i][0] = p0.x; xr[m][i][1] = p0.y; xr[m][i][2] = p0.z; xr[m][i][3] = p0.w;
      xr[m][i][4] = p1.x; xr[m][i][5] = p1.y; xr[m][i][6] = p1.z; xr[m][i][7] = p1.w;
    }

  // ---- contraction: 256 kappa-blocks of 128, Bt double-buffered ----
  char* Bt0 = R2 + 17408;
  char* Bt1 = R2 + 33792;
  f32x16 acc[2][2];
#pragma unroll
  for (int m = 0; m < 2; ++m)
#pragma unroll
    for (int n = 0; n < 2; ++n)
#pragma unroll
      for (int r = 0; r < 16; ++r) acc[m][n][r] = 0.f;

#pragma unroll
  for (int i = 0; i < 4; ++i) {  // stage kb=0
    int f = w * 16 + i * 4 + (lane >> 4);
    int slot = (lane & 15) ^ (f & 15);
    const char* g = (const char*)Wk2T + (size_t)f * 65536 + slot * 16;
    gl_lds16(g, Bt0 + (w * 16 + i * 4) * 256);
  }
  __syncthreads();

  for (int kb = 0; kb < 256; ++kb) {
    char* cur = (kb & 1) ? Bt1 : Bt0;
    char* nxt = (kb & 1) ? Bt0 : Bt1;
    if (kb < 255) {
#pragma unroll
      for (int i = 0; i < 4; ++i) {
        int f = w * 16 + i * 4 + (lane >> 4);
        int slot = (lane & 15) ^ (f & 15);
        const char* g = (const char*)Wk2T + (size_t)f * 65536 + (size_t)(kb + 1) * 256 + slot * 16;
        gl_lds16(g, nxt + (w * 16 + i * 4) * 256);
      }
    }
    const int kw = 2 * kb + (w >> 1);
    float hm[2];
#pragma unroll
    for (int m = 0; m < 2; ++m) {
      int e = (lane & 31) + 32 * m;
      unsigned short hb = *(const unsigned short*)(R1 + kw * 136 + e * 2);
      hm[m] = __uint_as_float((unsigned int)hb << 16);
    }
#pragma unroll
    for (int i = 0; i < 2; ++i) {
      short8 a[2], b[2];
#pragma unroll
      for (int m = 0; m < 2; ++m)
#pragma unroll
        for (int j = 0; j < 8; ++j)
          a[m][j] = bf16s(hm[m] * xr[m][i][j]);
#pragma unroll
      for (int n = 0; n < 2; ++n) {
        int f = n * 32 + (lane & 31);
        int slot = (2 * (2 * w + i) + half) ^ (f & 15);
        b[n] = *(const short8*)(cur + f * 256 + slot * 16);
      }
#pragma unroll
      for (int m = 0; m < 2; ++m)
#pragma unroll
        for (int n = 0; n < 2; ++n)
          acc[m][n] = __builtin_amdgcn_mfma_f32_32x32x16_bf16(a[m], b[n], acc[m][n], 0, 0, 0);
    }
    __syncthreads();
  }

  // ---- cross-wave reduce + segment-sum atomics ----
  float* part = (float*)R1;  // [4][64][66]
#pragma unroll
  for (int m = 0; m < 2; ++m)
#pragma unroll
    for (int n = 0; n < 2; ++n)
#pragma unroll
      for (int r = 0; r < 16; ++r) {
        int e = 32 * m + (r & 3) + 8 * (r >> 2) + 4 * half;
        int f = 32 * n + (lane & 31);
        part[(w * 64 + e) * 66 + f] = acc[m][n][r];
      }
  __syncthreads();
  for (int idx = t; idx < 4096; idx += 256) {
    int e = idx >> 6, f = idx & 63;
    float s = part[e * 66 + f] + part[(64 + e) * 66 + f] +
              part[(128 + e) * 66 + f] + part[(192 + e) * 66 + f];
    int eg = e0g + e;
    if (eg < EFFN) atomicAdd(&aggr[ei_ff[EFFN + eg] * 64 + f], s);
  }
}

// ---------------- final: Wroot/Wo/bk2 applies, FiLM, silu ----------------
__global__ __launch_bounds__(256) void k_final(
    const float* __restrict__ x_flow, const float* __restrict__ aggr,
    const float* __restrict__ xc, const float* __restrict__ z,
    const float* __restrict__ xsum, const float* __restrict__ bk2,
    const float* __restrict__ Wroot, const float* __restrict__ broot,
    const float* __restrict__ Wo, const float* __restrict__ bo,
    const float* __restrict__ tau, const float* __restrict__ Wt1,
    const float* __restrict__ bt1, const float* __restrict__ Wt2,
    const float* __restrict__ bt2, float* __restrict__ out) {
  __shared__ float WoS[4096], WrS[4096], B2S[4096], ssS[128], tembS[64];
  __shared__ float xcnS[4][65], xfS[4][65], xsS[4][65];
  const int t = threadIdx.x;
  for (int i = t; i < 4096; i += 256) { WoS[i] = Wo[i]; WrS[i] = Wroot[i]; B2S[i] = bk2[i]; }
  if (t < 64) {
    float y = tau[0] * Wt1[t] + bt1[t];
    tembS[t] = y / (1.f + expf(-y));
  }
  __syncthreads();
  if (t < 128) {
    float s = bt2[t];
#pragma unroll
    for (int d = 0; d < 64; ++d) s += tembS[d] * Wt2[d * 128 + t];
    ssS[t] = s;
  }
  const int r = t >> 6, f = t & 63;
  const int n = blockIdx.x * 4 + r;
  if (n < NFLOW) {
    float zr = z[n];
    xcnS[r][f] = xc[n * 64 + f] / (zr + 1e-9f);
    xfS[r][f] = x_flow[n * 64 + f];
    xsS[r][f] = xsum[n * 64 + f];
  }
  __syncthreads();
  if (n < NFLOW) {
    float cross = bo[f], root = broot[f], rb = 0.f;
#pragma unroll
    for (int d = 0; d < 64; ++d) {
      cross += xcnS[r][d] * WoS[d * 64 + f];
      root += xfS[r][d] * WrS[d * 64 + f];
      rb += xsS[r][d] * B2S[d * 64 + f];
    }
    float g = root + rb + aggr[n * 64 + f] + cross;
    g = fmaxf(g, 0.f);
    float y = g * (1.f + ssS[f]) + ssS[64 + f];
    out[n * 64 + f] = y / (1.f + expf(-y));
  }
}

extern "C" void kernel_launch(void* const* d_in, const int* in_sizes, int n_in,
                              void* d_out, int out_size, void* d_ws, size_t ws_size,
                              hipStream_t stream) {
  const float* x_flow = (const float*)d_in[0];
  const float* x_memb = (const float*)d_in[1];
  const float* ea_ff  = (const float*)d_in[2];
  const float* ea_mf  = (const float*)d_in[3];
  const float* tau    = (const float*)d_in[4];
  const int*   ei_ff  = (const int*)d_in[5];
  const int*   ei_mf  = (const int*)d_in[6];
  const float* Wk0 = (const float*)d_in[7],  *bk0 = (const float*)d_in[8];
  const float* Wk1 = (const float*)d_in[9],  *bk1 = (const float*)d_in[10];
  const float* Wk2 = (const float*)d_in[11], *bk2 = (const float*)d_in[12];
  const float* Wroot = (const float*)d_in[13], *broot = (const float*)d_in[14];
  const float* Wq = (const float*)d_in[15];
  const float* Wkk = (const float*)d_in[16];
  const float* Wv = (const float*)d_in[17];
  const float* We = (const float*)d_in[18];
  const float* Wo = (const float*)d_in[19], *bo = (const float*)d_in[20];
  const float* Wt1 = (const float*)d_in[21], *bt1 = (const float*)d_in[22];
  const float* Wt2 = (const float*)d_in[23], *bt2 = (const float*)d_in[24];

  float* ws = (float*)d_ws;
  float* xc    = ws;                    // NF*64
  float* aggr  = xc + NFLOW * 64;       // NF*64
  float* m     = aggr + NFLOW * 64;     // NF
  float* z     = m + NFLOW;             // NF
  float* score = z + NFLOW;             // EMF
  float* q     = score + EMFN;          // NF*64
  float* kb    = q + NFLOW * 64;        // NM*64
  float* vb    = kb + NMEMB * 64;       // NM*64
  float* xsum  = vb + NMEMB * 64;       // NF*64
  unsigned short* Wk1T = (unsigned short*)(xsum + NFLOW * 64);  // 512*512 bf16
  unsigned short* Wk2T = Wk1T + 512 * 512;                      // 64*32768 bf16
  float* out = (float*)d_out;

  k_init<<<(NFLOW * 64 + 255) / 256, 256, 0, stream>>>(xc, aggr, m, z, xsum);
  {
    dim3 g1(8, 8);
    k_transpose<<<g1, 256, 0, stream>>>(Wk1, Wk1T, 512, 512);
    dim3 g2(512, 1);
    k_transpose<<<g2, 256, 0, stream>>>(Wk2, Wk2T, 32768, 64);
  }
  k_linear64<<<(NFLOW + 3) / 4, 256, 0, stream>>>(x_flow, Wq, q, NFLOW);
  k_linear64<<<(NMEMB + 3) / 4, 256, 0, stream>>>(x_memb, Wkk, kb, NMEMB);
  k_linear64<<<(NMEMB + 3) / 4, 256, 0, stream>>>(x_memb, Wv, vb, NMEMB);
  k_score<<<EMFN / 4, 256, 0, stream>>>(q, kb, ea_mf, ei_mf, We, score, m);
  k_az<<<EMFN / 4, 256, 0, stream>>>(score, m, ei_mf, vb, z, xc);
  k_edge<<<(EFFN + 63) / 64, 256, 0, stream>>>(x_flow, ea_ff, ei_ff,
                                               Wk0, bk0, bk1, Wk1T, Wk2T, aggr, xsum);
  k_final<<<(NFLOW + 3) / 4, 256, 0, stream>>>(x_flow, aggr, xc, z, xsum, bk2,
                                               Wroot, broot, Wo, bo, tau, Wt1, bt1,
                                               Wt2, bt2, out);
}

// Round 3
// 1352.645 us; speedup vs baseline: 16.6517x; 1.3405x over previous
//
#include <hip/hip_runtime.h>
#include <hip/hip_bf16.h>

#define NFLOW 20000
#define NMEMB 5000
#define EFFN  100000
#define EMFN  80000

using short8 = __attribute__((ext_vector_type(8))) short;
using f32x16 = __attribute__((ext_vector_type(16))) float;

__device__ __forceinline__ short bf16s(float f) {
  __hip_bfloat16 h = __float2bfloat16(f);
  return *reinterpret_cast<short*>(&h);
}

__device__ __forceinline__ void gl_lds16(const void* g, void* l) {
  __builtin_amdgcn_global_load_lds(
      (const __attribute__((address_space(1))) unsigned int*)g,
      (__attribute__((address_space(3))) unsigned int*)l, 16, 0, 0);
}

__device__ __forceinline__ void atomicMaxFloat(float* addr, float val) {
  int* ai = (int*)addr;
  int old = __float_as_int(*addr);
  while (__int_as_float(old) < val) {
    int assumed = old;
    old = atomicCAS(ai, assumed, __float_as_int(val));
    if (old == assumed) break;
  }
}

// ---------------- init ----------------
__global__ __launch_bounds__(256) void k_init(float* __restrict__ xc,
                                              float* __restrict__ aggr,
                                              float* __restrict__ m,
                                              float* __restrict__ z,
                                              float* __restrict__ xsum) {
  int i = blockIdx.x * 256 + threadIdx.x;
  if (i < NFLOW * 64) { xc[i] = 0.f; aggr[i] = 0.f; xsum[i] = 0.f; }
  if (i < NFLOW) { m[i] = __int_as_float(0xff800000); z[i] = 0.f; }
}

// ------------- transpose+cvt: out[c*R+r] = bf16(in[r*C+c]) -------------
__global__ __launch_bounds__(256) void k_transpose(const float* __restrict__ in,
                                                   unsigned short* __restrict__ out,
                                                   int R, int C) {
  __shared__ unsigned short tile[64][66];
  const int t = threadIdx.x;
  const int r0 = blockIdx.x * 64, c0 = blockIdx.y * 64;
  {
    int r = t >> 2;
    int cb = (t & 3) * 16;
#pragma unroll
    for (int q = 0; q < 4; ++q) {
      float4 v = *(const float4*)(in + (size_t)(r0 + r) * C + c0 + cb + q * 4);
      tile[r][cb + q * 4 + 0] = (unsigned short)bf16s(v.x);
      tile[r][cb + q * 4 + 1] = (unsigned short)bf16s(v.y);
      tile[r][cb + q * 4 + 2] = (unsigned short)bf16s(v.z);
      tile[r][cb + q * 4 + 3] = (unsigned short)bf16s(v.w);
    }
  }
  __syncthreads();
  {
    int c = t >> 2;
    int rb = (t & 3) * 16;
#pragma unroll
    for (int q = 0; q < 4; ++q) {
      int r = rb + q * 4;
      ushort4 v = make_ushort4(tile[r][c], tile[r + 1][c], tile[r + 2][c], tile[r + 3][c]);
      *(ushort4*)(out + (size_t)(c0 + c) * R + r0 + r) = v;
    }
  }
}

// ---------------- Y(N,64) = X(N,64) @ W(64,64) ----------------
__global__ __launch_bounds__(256) void k_linear64(const float* __restrict__ X,
                                                  const float* __restrict__ W,
                                                  float* __restrict__ Y, int N) {
  __shared__ float Ws[64 * 64];
  __shared__ float Xs[4][65];
  const int t = threadIdx.x;
  for (int i = t; i < 4096; i += 256) Ws[i] = W[i];
  const int r = t >> 6, f = t & 63;
  const int n = blockIdx.x * 4 + r;
  Xs[r][f] = (n < N) ? X[n * 64 + f] : 0.f;
  __syncthreads();
  if (n < N) {
    float s = 0.f;
#pragma unroll
    for (int d = 0; d < 64; ++d) s += Xs[r][d] * Ws[d * 64 + f];
    Y[n * 64 + f] = s;
  }
}

// ---------------- attention scores + segment max ----------------
__global__ __launch_bounds__(256) void k_score(const float* __restrict__ q,
                                               const float* __restrict__ kb,
                                               const float* __restrict__ ea_mf,
                                               const int* __restrict__ ei_mf,
                                               const float* __restrict__ We,
                                               float* __restrict__ score,
                                               float* __restrict__ m) {
  const int t = threadIdx.x;
  const int e = blockIdx.x * 4 + (t >> 6);
  const int lane = t & 63;
  if (e >= EMFN) return;
  const int sm = ei_mf[e];
  const int df = ei_mf[EMFN + e];
  float ke = kb[sm * 64 + lane];
#pragma unroll
  for (int i = 0; i < 6; ++i) ke += ea_mf[e * 6 + i] * We[i * 64 + lane];
  float s = q[df * 64 + lane] * ke;
#pragma unroll
  for (int o = 32; o; o >>= 1) s += __shfl_xor(s, o, 64);
  s *= 0.125f;
  if (lane == 0) {
    score[e] = s;
    atomicMaxFloat(&m[df], s);
  }
}

// ---------------- a=exp(score-m); z += a; xc += a*v[src] ----------------
__global__ __launch_bounds__(256) void k_az(const float* __restrict__ score,
                                            const float* __restrict__ m,
                                            const int* __restrict__ ei_mf,
                                            const float* __restrict__ vb,
                                            float* __restrict__ z,
                                            float* __restrict__ xc) {
  const int t = threadIdx.x;
  const int e = blockIdx.x * 4 + (t >> 6);
  const int lane = t & 63;
  if (e >= EMFN) return;
  const int sm = ei_mf[e];
  const int df = ei_mf[EMFN + e];
  const float a = expf(score[e] - m[df]);
  if (lane == 0) atomicAdd(&z[df], a);
  atomicAdd(&xc[df * 64 + lane], a * vb[sm * 64 + lane]);
}

// ============ fused edge MLP + contraction (MFMA) ============
// R1 (69,632 B): {w0s|bk0s|eas} -> h1sT[512][68]bf16 (BtC @+34816) -> part[4][64][66]f32
// R2 (65,536 B): h0s swz bf16 -> { xs[64][72]bf16 (9216) | ring 3x16384 (49152) }
__device__ __forceinline__ void stage_k2(const unsigned short* Wk2T, char* slotp,
                                         int kb, int w, int lane) {
#pragma unroll
  for (int i = 0; i < 4; ++i) {
    int f = w * 16 + i * 4 + (lane >> 4);
    int pos = (lane & 15) ^ (f & 15);
    const char* g = (const char*)Wk2T + (size_t)f * 65536 + (size_t)kb * 256 + (size_t)pos * 16;
    gl_lds16(g, slotp + (w * 16 + i * 4) * 256);
  }
}

__global__ __launch_bounds__(256, 1) void k_edge(
    const float* __restrict__ x_flow, const float* __restrict__ ea_ff,
    const int* __restrict__ ei_ff,
    const float* __restrict__ Wk0, const float* __restrict__ bk0,
    const float* __restrict__ bk1,
    const unsigned short* __restrict__ Wk1T,   // [512 n][512 k] bf16
    const unsigned short* __restrict__ Wk2T,   // [64 f][32768 kappa] bf16
    float* __restrict__ aggr, float* __restrict__ xsum) {
  __shared__ __align__(16) char LDS[135168];
  char* R1 = LDS;
  char* R2 = LDS + 69632;
  const int t = threadIdx.x;
  const int w = t >> 6, lane = t & 63, half = lane >> 5;
  const int e0g = blockIdx.x * 64;

  // ---- stage Wk0, bk0, ea tile ----
  float* w0s  = (float*)R1;            // [6][512]
  float* bk0s = (float*)(R1 + 12288);  // [512]
  float* eas  = (float*)(R1 + 14336);  // [64][6]
  for (int i = t; i < 3072; i += 256) w0s[i] = Wk0[i];
  for (int i = t; i < 512; i += 256) bk0s[i] = bk0[i];
  for (int i = t; i < 384; i += 256) {
    int g = e0g * 6 + i;
    eas[i] = (g < EFFN * 6) ? ea_ff[g] : 0.f;
  }
  __syncthreads();

  // ---- h0 = relu(ea@Wk0+bk0) -> R2 swizzled bf16 ----
  {
    int e = t >> 2, c0 = (t & 3) * 128;
    float ea[6];
#pragma unroll
    for (int i = 0; i < 6; ++i) ea[i] = eas[e * 6 + i];
    for (int s8 = 0; s8 < 16; ++s8) {
      int kbase = c0 + s8 * 8;
      float s[8];
      float4 b0 = *(const float4*)(bk0s + kbase);
      float4 b1 = *(const float4*)(bk0s + kbase + 4);
      s[0]=b0.x; s[1]=b0.y; s[2]=b0.z; s[3]=b0.w; s[4]=b1.x; s[5]=b1.y; s[6]=b1.z; s[7]=b1.w;
#pragma unroll
      for (int i = 0; i < 6; ++i) {
        float4 w0 = *(const float4*)(w0s + i * 512 + kbase);
        float4 w1 = *(const float4*)(w0s + i * 512 + kbase + 4);
        s[0] = fmaf(ea[i], w0.x, s[0]); s[1] = fmaf(ea[i], w0.y, s[1]);
        s[2] = fmaf(ea[i], w0.z, s[2]); s[3] = fmaf(ea[i], w0.w, s[3]);
        s[4] = fmaf(ea[i], w1.x, s[4]); s[5] = fmaf(ea[i], w1.y, s[5]);
        s[6] = fmaf(ea[i], w1.z, s[6]); s[7] = fmaf(ea[i], w1.w, s[7]);
      }
      short8 v;
#pragma unroll
      for (int j = 0; j < 8; ++j) v[j] = bf16s(fmaxf(s[j], 0.f));
      int slot = (kbase >> 3) ^ (e & 15);
      *(short8*)(R2 + e * 1024 + slot * 16) = v;
    }
  }
  __syncthreads();

  // ---- h1 = relu(h0 @ Wk1 + bk1) -> h1sT[n][e] bf16 (2 passes of 256 n) ----
  char* BtC = R1 + 34816;  // [256 n][128 B]
  for (int pass = 0; pass < 2; ++pass) {
    const int np = pass * 256;
    f32x16 acc[2][2];
#pragma unroll
    for (int m = 0; m < 2; ++m)
#pragma unroll
      for (int n = 0; n < 2; ++n)
#pragma unroll
        for (int r = 0; r < 16; ++r) acc[m][n][r] = 0.f;
    for (int kc = 0; kc < 8; ++kc) {
#pragma unroll
      for (int i = 0; i < 8; ++i) {
        int row = w * 64 + i * 8 + (lane >> 3);
        int slot = (lane & 7) ^ (row & 7);
        const char* g = (const char*)Wk1T + (size_t)(np + row) * 1024 + kc * 128 + slot * 16;
        gl_lds16(g, BtC + (w * 64 + i * 8) * 128);
      }
      __syncthreads();
#pragma unroll
      for (int ks = 0; ks < 4; ++ks) {
        short8 a[2], b[2];
#pragma unroll
        for (int m = 0; m < 2; ++m) {
          int e = (lane & 31) + 32 * m;
          int slot = ((kc * 64 + ks * 16 + half * 8) >> 3) ^ (e & 15);
          a[m] = *(const short8*)(R2 + e * 1024 + slot * 16);
        }
#pragma unroll
        for (int n = 0; n < 2; ++n) {
          int nl = w * 64 + n * 32 + (lane & 31);
          int slot = (2 * ks + half) ^ (nl & 7);
          b[n] = *(const short8*)(BtC + nl * 128 + slot * 16);
        }
#pragma unroll
        for (int m = 0; m < 2; ++m)
#pragma unroll
          for (int n = 0; n < 2; ++n)
            acc[m][n] = __builtin_amdgcn_mfma_f32_32x32x16_bf16(a[m], b[n], acc[m][n], 0, 0, 0);
      }
      __syncthreads();
    }
    // epilogue: write h1sT rows np..np+255 (transposed, b64-packed)
#pragma unroll
    for (int n = 0; n < 2; ++n) {
      int nl = np + w * 64 + n * 32 + (lane & 31);
      float b1 = bk1[nl];
#pragma unroll
      for (int m = 0; m < 2; ++m) {
#pragma unroll
        for (int rq = 0; rq < 4; ++rq) {
          int e0 = 32 * m + 8 * rq + 4 * half;
          unsigned short u0 = (unsigned short)bf16s(fmaxf(acc[m][n][rq * 4 + 0] + b1, 0.f));
          unsigned short u1 = (unsigned short)bf16s(fmaxf(acc[m][n][rq * 4 + 1] + b1, 0.f));
          unsigned short u2 = (unsigned short)bf16s(fmaxf(acc[m][n][rq * 4 + 2] + b1, 0.f));
          unsigned short u3 = (unsigned short)bf16s(fmaxf(acc[m][n][rq * 4 + 3] + b1, 0.f));
          uint2 val = make_uint2((unsigned)u0 | ((unsigned)u1 << 16),
                                 (unsigned)u2 | ((unsigned)u3 << 16));
          *(uint2*)(R1 + nl * 136 + e0 * 2) = val;
        }
      }
    }
    __syncthreads();
  }

  // ---- stage xs (bf16 [64][72]) + xsum atomics ----
  unsigned short* xs = (unsigned short*)R2;
  {
    int row = t >> 2, c0 = (t & 3) * 16;
    int eg = e0g + row;
    bool valid = eg < EFFN;
    int src = valid ? ei_ff[eg] : 0;
    int dst = valid ? ei_ff[EFFN + eg] : 0;
#pragma unroll
    for (int q = 0; q < 4; ++q) {
      float4 v = valid ? *(const float4*)(x_flow + (size_t)src * 64 + c0 + q * 4)
                       : make_float4(0.f, 0.f, 0.f, 0.f);
      ushort4 u;
      u.x = (unsigned short)bf16s(v.x); u.y = (unsigned short)bf16s(v.y);
      u.z = (unsigned short)bf16s(v.z); u.w = (unsigned short)bf16s(v.w);
      *(ushort4*)(xs + row * 72 + c0 + q * 4) = u;
      if (valid) {
        atomicAdd(&xsum[dst * 64 + c0 + q * 4 + 0], v.x);
        atomicAdd(&xsum[dst * 64 + c0 + q * 4 + 1], v.y);
        atomicAdd(&xsum[dst * 64 + c0 + q * 4 + 2], v.z);
        atomicAdd(&xsum[dst * 64 + c0 + q * 4 + 3], v.w);
      }
    }
  }
  __syncthreads();  // full drain: clean vmcnt slate for the counted ring

  // ---- prefetch ring: 3 slots x 16KB at R2+9216 ----
  char* ring = R2 + 9216;
  stage_k2(Wk2T, ring, 0, w, lane);
  stage_k2(Wk2T, ring + 16384, 1, w, lane);

  // ---- x fragments into f32 registers ----
  float xr[2][2][8];
#pragma unroll
  for (int m = 0; m < 2; ++m)
#pragma unroll
    for (int i = 0; i < 2; ++i) {
      int row = (lane & 31) + 32 * m;
      int d0 = (32 * w + 16 * i + 8 * half) & 63;
      short8 xv = *(const short8*)(xs + row * 72 + d0);
#pragma unroll
      for (int j = 0; j < 8; ++j)
        xr[m][i][j] = __uint_as_float(((unsigned)(unsigned short)xv[j]) << 16);
    }

  f32x16 acc[2][2];
#pragma unroll
  for (int m = 0; m < 2; ++m)
#pragma unroll
    for (int n = 0; n < 2; ++n)
#pragma unroll
      for (int r = 0; r < 16; ++r) acc[m][n][r] = 0.f;

  // ---- contraction: 256 kappa-blocks of 128, ring-3, counted vmcnt ----
  for (int kb = 0; kb < 256; ++kb) {
    if (kb < 255) {
      asm volatile("s_waitcnt vmcnt(4)" ::: "memory");
    } else {
      asm volatile("s_waitcnt vmcnt(0)" ::: "memory");
    }
    __builtin_amdgcn_s_barrier();
    if (kb < 254) stage_k2(Wk2T, ring + ((kb + 2) % 3) * 16384, kb + 2, w, lane);

    char* cur = ring + (kb % 3) * 16384;
    const int kw = 2 * kb + (w >> 1);
    float hm[2];
#pragma unroll
    for (int m = 0; m < 2; ++m) {
      unsigned short hb = *(const unsigned short*)(R1 + kw * 136 + ((lane & 31) + 32 * m) * 2);
      hm[m] = __uint_as_float((unsigned int)hb << 16);
    }
#pragma unroll
    for (int i = 0; i < 2; ++i) {
      short8 b[2];
#pragma unroll
      for (int n = 0; n < 2; ++n) {
        int f = n * 32 + (lane & 31);
        int pos = (2 * (2 * w + i) + half) ^ (f & 15);
        b[n] = *(const short8*)(cur + f * 256 + pos * 16);
      }
#pragma unroll
      for (int m = 0; m < 2; ++m) {
        short8 a;
#pragma unroll
        for (int j = 0; j < 8; ++j) a[j] = bf16s(hm[m] * xr[m][i][j]);
#pragma unroll
        for (int n = 0; n < 2; ++n)
          acc[m][n] = __builtin_amdgcn_mfma_f32_32x32x16_bf16(a, b[n], acc[m][n], 0, 0, 0);
      }
    }
  }
  __syncthreads();

  // ---- cross-wave reduce + segment-sum atomics ----
  float* part = (float*)R1;  // [4][64][66]
#pragma unroll
  for (int m = 0; m < 2; ++m)
#pragma unroll
    for (int n = 0; n < 2; ++n)
#pragma unroll
      for (int r = 0; r < 16; ++r) {
        int e = 32 * m + (r & 3) + 8 * (r >> 2) + 4 * half;
        int f = 32 * n + (lane & 31);
        part[(w * 64 + e) * 66 + f] = acc[m][n][r];
      }
  __syncthreads();
  for (int idx = t; idx < 4096; idx += 256) {
    int e = idx >> 6, f = idx & 63;
    float s = part[e * 66 + f] + part[(64 + e) * 66 + f] +
              part[(128 + e) * 66 + f] + part[(192 + e) * 66 + f];
    int eg = e0g + e;
    if (eg < EFFN) atomicAdd(&aggr[ei_ff[EFFN + eg] * 64 + f], s);
  }
}

// ---------------- final: Wroot/Wo/bk2 applies, FiLM, silu ----------------
__global__ __launch_bounds__(256) void k_final(
    const float* __restrict__ x_flow, const float* __restrict__ aggr,
    const float* __restrict__ xc, const float* __restrict__ z,
    const float* __restrict__ xsum, const float* __restrict__ bk2,
    const float* __restrict__ Wroot, const float* __restrict__ broot,
    const float* __restrict__ Wo, const float* __restrict__ bo,
    const float* __restrict__ tau, const float* __restrict__ Wt1,
    const float* __restrict__ bt1, const float* __restrict__ Wt2,
    const float* __restrict__ bt2, float* __restrict__ out) {
  __shared__ float WoS[4096], WrS[4096], B2S[4096], ssS[128], tembS[64];
  __shared__ float xcnS[4][65], xfS[4][65], xsS[4][65];
  const int t = threadIdx.x;
  for (int i = t; i < 4096; i += 256) { WoS[i] = Wo[i]; WrS[i] = Wroot[i]; B2S[i] = bk2[i]; }
  if (t < 64) {
    float y = tau[0] * Wt1[t] + bt1[t];
    tembS[t] = y / (1.f + expf(-y));
  }
  __syncthreads();
  if (t < 128) {
    float s = bt2[t];
#pragma unroll
    for (int d = 0; d < 64; ++d) s += tembS[d] * Wt2[d * 128 + t];
    ssS[t] = s;
  }
  const int r = t >> 6, f = t & 63;
  const int n = blockIdx.x * 4 + r;
  if (n < NFLOW) {
    float zr = z[n];
    xcnS[r][f] = xc[n * 64 + f] / (zr + 1e-9f);
    xfS[r][f] = x_flow[n * 64 + f];
    xsS[r][f] = xsum[n * 64 + f];
  }
  __syncthreads();
  if (n < NFLOW) {
    float cross = bo[f], root = broot[f], rb = 0.f;
#pragma unroll
    for (int d = 0; d < 64; ++d) {
      cross += xcnS[r][d] * WoS[d * 64 + f];
      root += xfS[r][d] * WrS[d * 64 + f];
      rb += xsS[r][d] * B2S[d * 64 + f];
    }
    float g = root + rb + aggr[n * 64 + f] + cross;
    g = fmaxf(g, 0.f);
    float y = g * (1.f + ssS[f]) + ssS[64 + f];
    out[n * 64 + f] = y / (1.f + expf(-y));
  }
}

extern "C" void kernel_launch(void* const* d_in, const int* in_sizes, int n_in,
                              void* d_out, int out_size, void* d_ws, size_t ws_size,
                              hipStream_t stream) {
  const float* x_flow = (const float*)d_in[0];
  const float* x_memb = (const float*)d_in[1];
  const float* ea_ff  = (const float*)d_in[2];
  const float* ea_mf  = (const float*)d_in[3];
  const float* tau    = (const float*)d_in[4];
  const int*   ei_ff  = (const int*)d_in[5];
  const int*   ei_mf  = (const int*)d_in[6];
  const float* Wk0 = (const float*)d_in[7],  *bk0 = (const float*)d_in[8];
  const float* Wk1 = (const float*)d_in[9],  *bk1 = (const float*)d_in[10];
  const float* Wk2 = (const float*)d_in[11], *bk2 = (const float*)d_in[12];
  const float* Wroot = (const float*)d_in[13], *broot = (const float*)d_in[14];
  const float* Wq = (const float*)d_in[15];
  const float* Wkk = (const float*)d_in[16];
  const float* Wv = (const float*)d_in[17];
  const float* We = (const float*)d_in[18];
  const float* Wo = (const float*)d_in[19], *bo = (const float*)d_in[20];
  const float* Wt1 = (const float*)d_in[21], *bt1 = (const float*)d_in[22];
  const float* Wt2 = (const float*)d_in[23], *bt2 = (const float*)d_in[24];

  float* ws = (float*)d_ws;
  float* xc    = ws;                    // NF*64
  float* aggr  = xc + NFLOW * 64;       // NF*64
  float* m     = aggr + NFLOW * 64;     // NF
  float* z     = m + NFLOW;             // NF
  float* score = z + NFLOW;             // EMF
  float* q     = score + EMFN;          // NF*64
  float* kb    = q + NFLOW * 64;        // NM*64
  float* vb    = kb + NMEMB * 64;       // NM*64
  float* xsum  = vb + NMEMB * 64;       // NF*64
  unsigned short* Wk1T = (unsigned short*)(xsum + NFLOW * 64);  // 512*512 bf16
  unsigned short* Wk2T = Wk1T + 512 * 512;                      // 64*32768 bf16
  float* out = (float*)d_out;

  k_init<<<(NFLOW * 64 + 255) / 256, 256, 0, stream>>>(xc, aggr, m, z, xsum);
  {
    dim3 g1(8, 8);
    k_transpose<<<g1, 256, 0, stream>>>(Wk1, Wk1T, 512, 512);
    dim3 g2(512, 1);
    k_transpose<<<g2, 256, 0, stream>>>(Wk2, Wk2T, 32768, 64);
  }
  k_linear64<<<(NFLOW + 3) / 4, 256, 0, stream>>>(x_flow, Wq, q, NFLOW);
  k_linear64<<<(NMEMB + 3) / 4, 256, 0, stream>>>(x_memb, Wkk, kb, NMEMB);
  k_linear64<<<(NMEMB + 3) / 4, 256, 0, stream>>>(x_memb, Wv, vb, NMEMB);
  k_score<<<EMFN / 4, 256, 0, stream>>>(q, kb, ea_mf, ei_mf, We, score, m);
  k_az<<<EMFN / 4, 256, 0, stream>>>(score, m, ei_mf, vb, z, xc);
  k_edge<<<(EFFN + 63) / 64, 256, 0, stream>>>(x_flow, ea_ff, ei_ff,
                                               Wk0, bk0, bk1, Wk1T, Wk2T, aggr, xsum);
  k_final<<<(NFLOW + 3) / 4, 256, 0, stream>>>(x_flow, aggr, xc, z, xsum, bk2,
                                               Wroot, broot, Wo, bo, tau, Wt1, bt1,
                                               Wt2, bt2, out);
}